// Round 1
// baseline (142.784 us; speedup 1.0000x reference)
//
#include <hip/hip_runtime.h>

// Fused masked 3x3 conv ×2 (MinkowskiConv stride-1 equivalent):
//   m  = float(mask)
//   h  = relu((conv3x3(x*m, w1) + b1) * m)
//   out = (conv3x3(h, w2) + b2) * m
// One kernel, LDS-tiled with 2-pixel halo so the intermediate h never
// touches HBM.

#define TB_W 64            // output tile width
#define TB_H 32            // output tile height
#define SX (TB_W + 4)      // 68: staged x*m / m region width
#define SY (TB_H + 4)      // 36
#define HX (TB_W + 2)      // 66: staged h region width
#define HY (TB_H + 2)      // 34

__global__ __launch_bounds__(256) void fused_mconv2(
    const float* __restrict__ x, const int* __restrict__ mask,
    const float* __restrict__ w1p, const float* __restrict__ b1p,
    const float* __restrict__ w2p, const float* __restrict__ b2p,
    float* __restrict__ out, int H, int W)
{
    __shared__ float s_xm[SY][SX];   // x*m over halo-2 region
    __shared__ float s_m [SY][SX];   // m   over halo-2 region
    __shared__ float s_h [HY][HX];   // h   over halo-1 region

    const int tid = threadIdx.y * 64 + threadIdx.x;   // block (64,4)
    const int c0  = blockIdx.x * TB_W;
    const int r0  = blockIdx.y * TB_H;
    const size_t plane = (size_t)H * W;
    const float* xb = x    + (size_t)blockIdx.z * plane;
    const int*   mb = mask + (size_t)blockIdx.z * plane;
    float*       ob = out  + (size_t)blockIdx.z * plane;

    // Weights: uniform addresses -> scalar loads, L1-cached broadcast.
    float W1[9], W2[9];
    #pragma unroll
    for (int i = 0; i < 9; ++i) { W1[i] = w1p[i]; W2[i] = w2p[i]; }
    const float B1 = b1p[0], B2 = b2p[0];

    // ---- stage x*m and m (68x36 region, origin at (r0-2, c0-2)) ----
    for (int idx = tid; idx < SY * SX; idx += 256) {
        const int row = idx / SX, col = idx - row * SX;
        const int r = r0 - 2 + row, c = c0 - 2 + col;
        float xv = 0.f, mv = 0.f;
        if (r >= 0 && r < H && c >= 0 && c < W) {
            const size_t g = (size_t)r * W + c;
            mv = (float)mb[g];
            xv = xb[g] * mv;
        }
        s_xm[row][col] = xv;
        s_m [row][col] = mv;
    }
    __syncthreads();

    // ---- h = relu((conv3x3(x*m, w1) + b1) * m) over 66x34 region ----
    // h(i,j) lives at global (r0-1+i, c0-1+j); its conv taps are
    // s_xm[i+di][j+dj], di,dj in 0..2; its mask is s_m[i+1][j+1].
    for (int idx = tid; idx < HY * HX; idx += 256) {
        const int row = idx / HX, col = idx - row * HX;
        float acc = B1;
        #pragma unroll
        for (int di = 0; di < 3; ++di)
            #pragma unroll
            for (int dj = 0; dj < 3; ++dj)
                acc += W1[di * 3 + dj] * s_xm[row + di][col + dj];
        const float hv = acc * s_m[row + 1][col + 1];
        s_h[row][col] = hv > 0.f ? hv : 0.f;
    }
    __syncthreads();

    // ---- out = (conv3x3(h, w2) + b2) * m over the 64x32 tile ----
    // out(i,j) at global (r0+i, c0+j); taps s_h[i+di][j+dj]; mask s_m[i+2][j+2].
    const int tx = threadIdx.x;
    for (int i = threadIdx.y; i < TB_H; i += 4) {
        float acc = B2;
        #pragma unroll
        for (int di = 0; di < 3; ++di)
            #pragma unroll
            for (int dj = 0; dj < 3; ++dj)
                acc += W2[di * 3 + dj] * s_h[i + di][tx + dj];
        const float res = acc * s_m[i + 2][tx + 2];
        ob[(size_t)(r0 + i) * W + (c0 + tx)] = res;
    }
}

extern "C" void kernel_launch(void* const* d_in, const int* in_sizes, int n_in,
                              void* d_out, int out_size, void* d_ws, size_t ws_size,
                              hipStream_t stream) {
    const float* x    = (const float*)d_in[0];
    const int*   mask = (const int*)  d_in[1];
    const float* w1   = (const float*)d_in[2];
    const float* b1   = (const float*)d_in[3];
    const float* w2   = (const float*)d_in[4];
    const float* b2   = (const float*)d_in[5];
    float*       out  = (float*)d_out;

    const int H = 2048, W = 2048;
    const int B = in_sizes[0] / (H * W);

    dim3 block(64, 4, 1);
    dim3 grid(W / TB_W, H / TB_H, B);   // 32 x 64 x 8
    hipLaunchKernelGGL(fused_mconv2, grid, block, 0, stream,
                       x, mask, w1, b1, w2, b2, out, H, W);
}

// Round 2
// 103.164 us; speedup vs baseline: 1.3840x; 1.3840x over previous
//
#include <hip/hip_runtime.h>

// Fused masked 3x3 conv x2 (MinkowskiConv stride-1 equivalent), fp32:
//   m   = float(mask)
//   h   = relu((conv3x3(x*m, w1) + b1) * m)
//   out = (conv3x3(h, w2) + b2) * m
// One kernel, LDS-tiled, 2-pixel halo. Mask is folded into the h buffer's
// sign (enc = m ? h : -1, h >= 0 by ReLU) so only two LDS arrays are needed.

#define TB_W 128           // output tile width
#define TB_H 32            // output tile height
#define SX   136           // staged width:  TB_W + 8 (16B-aligned halo)
#define SY   36            // staged height: TB_H + 4
#define NV4  (SX / 4)      // 34 float4 per staged row
#define NSTG (SY * NV4)    // 1224 float4 per array
#define HX   130           // h region width  (TB_W + 2)
#define HY   34            // h region height (TB_H + 2)
#define NH   (HX * HY)     // 4420 h points

__global__ __launch_bounds__(256) void fused_mconv2(
    const float* __restrict__ x, const int* __restrict__ mask,
    const float* __restrict__ w1p, const float* __restrict__ b1p,
    const float* __restrict__ w2p, const float* __restrict__ b2p,
    float* __restrict__ out, int H, int W)
{
    __shared__ float s_xm[SY][SX];   // x*m over halo-2 region
    __shared__ float s_hm[SY][SX];   // stage: m; after conv1: enc(h,m)

    const int tid = threadIdx.y * 64 + threadIdx.x;      // block (64,4)
    const int c0  = blockIdx.x * TB_W;
    const int r0  = blockIdx.y * TB_H;
    const size_t plane = (size_t)H * W;
    const float* xb = x    + (size_t)blockIdx.z * plane;
    const int*   mb = mask + (size_t)blockIdx.z * plane;
    float*       ob = out  + (size_t)blockIdx.z * plane;

    float W1[9], W2[9];
    #pragma unroll
    for (int i = 0; i < 9; ++i) { W1[i] = w1p[i]; W2[i] = w2p[i]; }
    const float B1 = b1p[0], B2 = b2p[0];

    // ---- stage: x*m and m, float4/int4 vector loads, region origin (r0-2, c0-4) ----
    for (int idx = tid; idx < NSTG; idx += 256) {
        const int row  = idx / NV4;
        const int col4 = idx - row * NV4;
        const int r = r0 - 2 + row;
        const int c = c0 - 4 + (col4 << 2);
        float4 xm = make_float4(0.f, 0.f, 0.f, 0.f);
        float4 mm = make_float4(0.f, 0.f, 0.f, 0.f);
        if (r >= 0 && r < H && c >= 0 && c < W) {   // c%4==0, W%4==0 -> all-or-nothing
            const size_t g = (size_t)r * W + c;
            const float4 xv = *reinterpret_cast<const float4*>(xb + g);
            const int4   mi = *reinterpret_cast<const int4*>(mb + g);
            mm = make_float4((float)mi.x, (float)mi.y, (float)mi.z, (float)mi.w);
            xm = make_float4(xv.x * mm.x, xv.y * mm.y, xv.z * mm.z, xv.w * mm.w);
        }
        *reinterpret_cast<float4*>(&s_xm[row][col4 << 2]) = xm;
        *reinterpret_cast<float4*>(&s_hm[row][col4 << 2]) = mm;
    }
    __syncthreads();

    // ---- conv1: enc = m ? relu(conv(x*m)+b1) : -1, over 130x34 h region ----
    // h point (hrow,hcol) sits at stage coords (hrow+1, hcol+3); taps at
    // (hrow+di, hcol+2+dj). Each thread reads+writes only its own s_hm point.
    for (int idx = tid; idx < NH; idx += 256) {
        const int hrow = idx / HX;
        const int hcol = idx - hrow * HX;
        const float m = s_hm[hrow + 1][hcol + 3];
        float acc = B1;
        #pragma unroll
        for (int di = 0; di < 3; ++di)
            #pragma unroll
            for (int dj = 0; dj < 3; ++dj)
                acc += W1[di * 3 + dj] * s_xm[hrow + di][hcol + 2 + dj];
        const float h = acc > 0.f ? acc : 0.f;
        s_hm[hrow + 1][hcol + 3] = (m > 0.5f) ? h : -1.0f;
    }
    __syncthreads();

    // ---- conv2: out = (conv(max(enc,0)) + b2) * (enc_center >= 0), float4 stores ----
    const int col4  = tid & 31;        // 0..31  -> output cols iw..iw+3
    const int iw    = col4 << 2;
    const int rbase = tid >> 5;        // 0..7
    for (int i = rbase; i < TB_H; i += 8) {
        float tap[3][6];               // rows i+1..i+3, cols iw+3..iw+8 (raw enc)
        #pragma unroll
        for (int di = 0; di < 3; ++di) {
            const float* rowp = &s_hm[i + 1 + di][0];
            const float4 mid = *reinterpret_cast<const float4*>(rowp + iw + 4);
            tap[di][0] = rowp[iw + 3];
            tap[di][1] = mid.x; tap[di][2] = mid.y;
            tap[di][3] = mid.z; tap[di][4] = mid.w;
            tap[di][5] = rowp[iw + 8];
        }
        float rel[3][6];
        #pragma unroll
        for (int di = 0; di < 3; ++di)
            #pragma unroll
            for (int k = 0; k < 6; ++k)
                rel[di][k] = tap[di][k] > 0.f ? tap[di][k] : 0.f;
        float r_[4];
        #pragma unroll
        for (int q = 0; q < 4; ++q) {
            float acc = B2;
            #pragma unroll
            for (int di = 0; di < 3; ++di)
                #pragma unroll
                for (int dj = 0; dj < 3; ++dj)
                    acc += W2[di * 3 + dj] * rel[di][q + dj];
            r_[q] = (tap[1][q + 1] >= 0.f) ? acc : 0.f;   // center enc carries m
        }
        *reinterpret_cast<float4*>(ob + (size_t)(r0 + i) * W + (c0 + iw)) =
            make_float4(r_[0], r_[1], r_[2], r_[3]);
    }
}

extern "C" void kernel_launch(void* const* d_in, const int* in_sizes, int n_in,
                              void* d_out, int out_size, void* d_ws, size_t ws_size,
                              hipStream_t stream) {
    const float* x    = (const float*)d_in[0];
    const int*   mask = (const int*)  d_in[1];
    const float* w1   = (const float*)d_in[2];
    const float* b1   = (const float*)d_in[3];
    const float* w2   = (const float*)d_in[4];
    const float* b2   = (const float*)d_in[5];
    float*       out  = (float*)d_out;

    const int H = 2048, W = 2048;
    const int B = in_sizes[0] / (H * W);

    dim3 block(64, 4, 1);
    dim3 grid(W / TB_W, H / TB_H, B);   // 16 x 64 x 8
    hipLaunchKernelGGL(fused_mconv2, grid, block, 0, stream,
                       x, mask, w1, b1, w2, b2, out, H, W);
}

// Round 3
// 86.236 us; speedup vs baseline: 1.6557x; 1.1963x over previous
//
#include <hip/hip_runtime.h>

// Fused masked 3x3 conv x2 (MinkowskiConv stride-1 equivalent), fp32:
//   m   = float(mask)
//   h   = relu((conv3x3(x*m, w1) + b1) * m)
//   out = (conv3x3(h, w2) + b2) * m
// LDS-tiled, 2-pixel halo, mask folded into h's sign (enc = m ? h : -1).
// conv2 is column-per-lane with register rolling down rows: all LDS reads
// are consecutive-address b32 (conflict-free), no 16B-strided taps.

#define TB_W 128           // output tile width
#define TB_H 16            // output tile height
#define SX   136           // staged width:  TB_W + 8 (16B-aligned halo)
#define SY   20            // staged height: TB_H + 4
#define NV4  (SX / 4)      // 34 float4 per staged row
#define NSTG (SY * NV4)    // 680 float4 per array
#define HX   130           // h region width  (TB_W + 2)
#define HY   18            // h region height (TB_H + 2)
#define NH   (HX * HY)     // 2340 h points

__global__ __launch_bounds__(256) void fused_mconv2(
    const float* __restrict__ x, const int* __restrict__ mask,
    const float* __restrict__ w1p, const float* __restrict__ b1p,
    const float* __restrict__ w2p, const float* __restrict__ b2p,
    float* __restrict__ out, int H, int W)
{
    __shared__ float s_xm[SY][SX];   // x*m over halo-2 region
    __shared__ float s_hm[SY][SX];   // stage: m; after conv1: enc(h,m)

    const int tid  = threadIdx.y * 64 + threadIdx.x;     // block (64,4)
    const int c0   = blockIdx.x * TB_W;
    const int row0 = blockIdx.y * TB_H;
    const size_t plane = (size_t)H * W;
    const float* xb = x    + (size_t)blockIdx.z * plane;
    const int*   mb = mask + (size_t)blockIdx.z * plane;
    float*       ob = out  + (size_t)blockIdx.z * plane;

    float W1[9], W2[9];
    #pragma unroll
    for (int i = 0; i < 9; ++i) { W1[i] = w1p[i]; W2[i] = w2p[i]; }
    const float B1 = b1p[0], B2 = b2p[0];

    // ---- stage: x*m and m, float4/int4 vector loads, origin (row0-2, c0-4) ----
    for (int idx = tid; idx < NSTG; idx += 256) {
        const int row  = idx / NV4;
        const int col4 = idx - row * NV4;
        const int r = row0 - 2 + row;
        const int c = c0 - 4 + (col4 << 2);
        float4 xm = make_float4(0.f, 0.f, 0.f, 0.f);
        float4 mm = make_float4(0.f, 0.f, 0.f, 0.f);
        if (r >= 0 && r < H && c >= 0 && c < W) {   // c%4==0, W%4==0 -> all-or-nothing
            const size_t g = (size_t)r * W + c;
            const float4 xv = *reinterpret_cast<const float4*>(xb + g);
            const int4   mi = *reinterpret_cast<const int4*>(mb + g);
            mm = make_float4((float)mi.x, (float)mi.y, (float)mi.z, (float)mi.w);
            xm = make_float4(xv.x * mm.x, xv.y * mm.y, xv.z * mm.z, xv.w * mm.w);
        }
        *reinterpret_cast<float4*>(&s_xm[row][col4 << 2]) = xm;
        *reinterpret_cast<float4*>(&s_hm[row][col4 << 2]) = mm;
    }
    __syncthreads();

    // ---- conv1: enc = m ? relu(conv(x*m)+b1) : -1, over 130x18 h region ----
    // h point (hrow,hcol) sits at stage coords (hrow+1, hcol+3); taps at
    // (hrow+di, hcol+2+dj). Consecutive lanes -> consecutive addresses.
    for (int idx = tid; idx < NH; idx += 256) {
        const int hrow = idx / HX;
        const int hcol = idx - hrow * HX;
        const float m = s_hm[hrow + 1][hcol + 3];
        float acc = B1;
        #pragma unroll
        for (int di = 0; di < 3; ++di)
            #pragma unroll
            for (int dj = 0; dj < 3; ++dj)
                acc += W1[di * 3 + dj] * s_xm[hrow + di][hcol + 2 + dj];
        const float h = acc > 0.f ? acc : 0.f;
        s_hm[hrow + 1][hcol + 3] = (m > 0.5f) ? h : -1.0f;
    }
    __syncthreads();

    // ---- conv2: column-per-lane register rolling, conflict-free reads ----
    // out(i,j) = B2 + sum_di w2row[di] . relu(s_hm[i+1+di][j+3..j+5]),
    // masked by enc sign at center s_hm[i+2][j+4].
    // Rolling over stage rows s: d_k(s) = w2row[k] . relu(row s taps);
    // out(s-3) = Q + d2(s) + B2 with Q = d0(s-2)+d1(s-1), P = d0(s-1).
    {
        const int j     = tid & 127;        // output column
        const int strip = tid >> 7;         // 0..1
        const int i0    = strip * (TB_H / 2);
        float P = 0.f, Q = 0.f, cm = 0.f;
        #pragma unroll
        for (int t = 1; t <= TB_H / 2 + 2; ++t) {
            const int s = i0 + t;
            const float* rowp = &s_hm[s][0];
            const float t0 = rowp[j + 3];
            const float t1 = rowp[j + 4];
            const float t2 = rowp[j + 5];
            const float r0 = t0 > 0.f ? t0 : 0.f;
            const float r1 = t1 > 0.f ? t1 : 0.f;
            const float r2 = t2 > 0.f ? t2 : 0.f;
            const float d0 = W2[0] * r0 + W2[1] * r1 + W2[2] * r2;
            const float d1 = W2[3] * r0 + W2[4] * r1 + W2[5] * r2;
            const float d2 = W2[6] * r0 + W2[7] * r1 + W2[8] * r2;
            if (t >= 3) {
                const int i = s - 3;
                const float v = (cm >= 0.f) ? (Q + d2 + B2) : 0.f;
                ob[(size_t)(row0 + i) * W + (c0 + j)] = v;
            }
            Q  = P + d1;
            P  = d0;
            cm = t1;
        }
    }
}

extern "C" void kernel_launch(void* const* d_in, const int* in_sizes, int n_in,
                              void* d_out, int out_size, void* d_ws, size_t ws_size,
                              hipStream_t stream) {
    const float* x    = (const float*)d_in[0];
    const int*   mask = (const int*)  d_in[1];
    const float* w1   = (const float*)d_in[2];
    const float* b1   = (const float*)d_in[3];
    const float* w2   = (const float*)d_in[4];
    const float* b2   = (const float*)d_in[5];
    float*       out  = (float*)d_out;

    const int H = 2048, W = 2048;
    const int B = in_sizes[0] / (H * W);

    dim3 block(64, 4, 1);
    dim3 grid(W / TB_W, H / TB_H, B);   // 16 x 128 x 8
    hipLaunchKernelGGL(fused_mconv2, grid, block, 0, stream,
                       x, mask, w1, b1, w2, b2, out, H, W);
}